// Round 4
// baseline (1168.673 us; speedup 1.0000x reference)
//
#include <hip/hip_runtime.h>

#define NN 200000
#define NE 400000
#define HD 128
#define NL 3
#define NG 4096
#define BN_EPS 1e-5f

// ---------------- workspace layout (bytes) ----------------
#define OFF_DINV  0UL                  // NN floats
#define OFF_H     800000UL             // NN*HD floats
#define OFF_U     103200000UL          // NN*HD floats
#define OFF_ACC   205600000UL          // NN*HD floats (holds y = dinv*agg)
#define OFF_POOL  308000000UL          // NG*HD floats (group means)
#define OFF_GSTART 310097152UL         // (NG+1) ints
#define OFF_CSUM  310113540UL          // NL*HD floats
#define OFF_CSQ   310115076UL          // NL*HD floats
#define OFF_SCALE 310116612UL          // HD floats
#define OFF_SHIFT 310117124UL          // HD floats
#define OFF_CNTI  310117636UL          // NN ints (in-degree, excl self)
#define OFF_OFFS  310917636UL          // (NN+1) ints + pad
#define OFF_CUR   311717652UL          // NN ints (fill cursors)
#define OFF_SRCS  312517652UL          // NE ints (CSR sources)
#define OFF_BSUM  314117652UL          // scan partials (256 ints)

#define SCAN_B 196                     // ceil(NN/1024)

__global__ void count_deg_i(const int* __restrict__ col, int* __restrict__ cnt) {
    int e = blockIdx.x * blockDim.x + threadIdx.x;
    if (e < NE) atomicAdd(&cnt[col[e]], 1);
}

__global__ void finalize_dinv(const int* __restrict__ cnt, float* __restrict__ dinv) {
    int i = blockIdx.x * blockDim.x + threadIdx.x;
    if (i < NN) dinv[i] = rsqrtf((float)(cnt[i] + 1));   // +1 self-loop
}

// ---- exclusive scan of cnt[NN] -> offs[NN+1] (three phases) ----
__global__ void scan_phase1(const int* __restrict__ cnt, int* __restrict__ bsum) {
    __shared__ int sh[256];
    int b = blockIdx.x, t = threadIdx.x;
    int base = b * 1024 + t * 4;
    int s = 0;
#pragma unroll
    for (int j = 0; j < 4; ++j) if (base + j < NN) s += cnt[base + j];
    sh[t] = s;
    __syncthreads();
    for (int st = 128; st > 0; st >>= 1) {
        if (t < st) sh[t] += sh[t + st];
        __syncthreads();
    }
    if (t == 0) bsum[b] = sh[0];
}

__global__ void scan_phase2(int* __restrict__ bsum, int* __restrict__ offs) {
    if (threadIdx.x == 0) {
        int run = 0;
        for (int i = 0; i < SCAN_B; ++i) { int v = bsum[i]; bsum[i] = run; run += v; }
        offs[NN] = NE;
    }
}

__global__ void scan_phase3(const int* __restrict__ cnt, const int* __restrict__ bsum,
                            int* __restrict__ offs) {
    __shared__ int sh[256];
    int b = blockIdx.x, t = threadIdx.x;
    int base = b * 1024 + t * 4;
    int v[4];
    int s = 0;
#pragma unroll
    for (int j = 0; j < 4; ++j) { v[j] = (base + j < NN) ? cnt[base + j] : 0; s += v[j]; }
    sh[t] = s;
    __syncthreads();
    for (int st = 1; st < 256; st <<= 1) {
        int x = (t >= st) ? sh[t - st] : 0;
        __syncthreads();
        sh[t] += x;
        __syncthreads();
    }
    int run = sh[t] - s + bsum[b];   // exclusive prefix for this thread's range
#pragma unroll
    for (int j = 0; j < 4; ++j) {
        if (base + j < NN) { offs[base + j] = run; run += v[j]; }
    }
}

__global__ void fill_csr(const int* __restrict__ row, const int* __restrict__ col,
                         const int* __restrict__ offs, int* __restrict__ cur,
                         int* __restrict__ srcs) {
    int e = blockIdx.x * blockDim.x + threadIdx.x;
    if (e >= NE) return;
    int c = col[e];
    int p = offs[c] + atomicAdd(&cur[c], 1);
    srcs[p] = row[e];
}

// O[r][:] = A[r][:] @ W (+bias) (*dinv[r]).
// 512 threads = 32 rowgroups(8 rows each) x 16 colgroups -> 256 rows/block.
// Per k4: 8 ds_read_b128 feed 256 FMAs (0.5 B/FMA) — under LDS ceiling.
template <bool ADD_BIAS, bool SCALE_DINV>
__launch_bounds__(512, 4)
__global__ void gemm128(const float* __restrict__ A, const float* __restrict__ W,
                        const float* __restrict__ bias, const float* __restrict__ dinv,
                        float* __restrict__ O, int M) {
    __shared__ float Wl[HD * HD];
    float4* Wl4 = (float4*)Wl;
    const float4* W4 = (const float4*)W;
    for (int i = threadIdx.x; i < HD * HD / 4; i += 512) Wl4[i] = W4[i];
    __syncthreads();

    int rg = threadIdx.x >> 4;        // 0..31
    int cg = threadIdx.x & 15;        // 0..15
    int r0 = blockIdx.x * 256 + rg * 8;
    if (r0 >= M) return;              // NN % 8 == 0: whole 8-row slice valid or not

    const float4* A4 = (const float4*)(A + (size_t)r0 * HD);
    float4 acc0[8], acc1[8];
#pragma unroll
    for (int i = 0; i < 8; ++i) {
        acc0[i] = make_float4(0.f, 0.f, 0.f, 0.f);
        acc1[i] = make_float4(0.f, 0.f, 0.f, 0.f);
    }

    for (int k4 = 0; k4 < 32; ++k4) {
        float4 a[8];
#pragma unroll
        for (int i = 0; i < 8; ++i) a[i] = A4[i * 32 + k4];
#pragma unroll
        for (int j = 0; j < 4; ++j) {
            float4 w0 = Wl4[(k4 * 4 + j) * 32 + cg];
            float4 w1 = Wl4[(k4 * 4 + j) * 32 + 16 + cg];
#pragma unroll
            for (int i = 0; i < 8; ++i) {
                float av = (j == 0) ? a[i].x : (j == 1) ? a[i].y : (j == 2) ? a[i].z : a[i].w;
                acc0[i].x = fmaf(av, w0.x, acc0[i].x);
                acc0[i].y = fmaf(av, w0.y, acc0[i].y);
                acc0[i].z = fmaf(av, w0.z, acc0[i].z);
                acc0[i].w = fmaf(av, w0.w, acc0[i].w);
                acc1[i].x = fmaf(av, w1.x, acc1[i].x);
                acc1[i].y = fmaf(av, w1.y, acc1[i].y);
                acc1[i].z = fmaf(av, w1.z, acc1[i].z);
                acc1[i].w = fmaf(av, w1.w, acc1[i].w);
            }
        }
    }

    float4 b0 = make_float4(0.f, 0.f, 0.f, 0.f), b1 = b0;
    if (ADD_BIAS) {
        b0 = ((const float4*)bias)[cg];
        b1 = ((const float4*)bias)[16 + cg];
    }
#pragma unroll
    for (int i = 0; i < 8; ++i) {
        int r = r0 + i;
        float s = SCALE_DINV ? dinv[r] : 1.0f;
        float4 o0 = acc0[i], o1 = acc1[i];
        if (ADD_BIAS) {
            o0.x += b0.x; o0.y += b0.y; o0.z += b0.z; o0.w += b0.w;
            o1.x += b1.x; o1.y += b1.y; o1.z += b1.z; o1.w += b1.w;
        }
        if (SCALE_DINV) {
            o0.x *= s; o0.y *= s; o0.z *= s; o0.w *= s;
            o1.x *= s; o1.y *= s; o1.z *= s; o1.w *= s;
        }
        float4* O4 = (float4*)(O + (size_t)r * HD);
        O4[cg] = o0;
        O4[16 + cg] = o1;
    }
}

// acc[i] = y_i = dinv[i]*(u[i] + sum_{e: col=i} u[src[e]]); fused BN col stats.
#define GATHER_BLOCKS 1024
__global__ void gather_bn(const int* __restrict__ offs, const int* __restrict__ srcs,
                          const float* __restrict__ u, const float* __restrict__ dinv,
                          float* __restrict__ acc,
                          float* __restrict__ colsum, float* __restrict__ colsumsq) {
    const float4* u4 = (const float4*)u;
    float4* acc4 = (float4*)acc;
    int n = threadIdx.x >> 5;     // node slot 0..7
    int q = threadIdx.x & 31;     // float4 lane within row
    float4 t1 = make_float4(0.f, 0.f, 0.f, 0.f);
    float4 t2 = make_float4(0.f, 0.f, 0.f, 0.f);

    for (int node = blockIdx.x * 8 + n; node < NN; node += GATHER_BLOCKS * 8) {
        float4 s = u4[(size_t)node * 32 + q];     // self-loop seed
        int k1 = offs[node + 1];
        for (int k = offs[node]; k < k1; ++k) {
            int src = srcs[k];
            float4 v = u4[(size_t)src * 32 + q];
            s.x += v.x; s.y += v.y; s.z += v.z; s.w += v.w;
        }
        float d = dinv[node];
        s.x *= d; s.y *= d; s.z *= d; s.w *= d;
        acc4[(size_t)node * 32 + q] = s;
        t1.x += s.x; t1.y += s.y; t1.z += s.z; t1.w += s.w;
        t2.x += s.x * s.x; t2.y += s.y * s.y; t2.z += s.z * s.z; t2.w += s.w * s.w;
    }

    __shared__ float sh1[8][HD];
    __shared__ float sh2[8][HD];
    *(float4*)&sh1[n][q * 4] = t1;
    *(float4*)&sh2[n][q * 4] = t2;
    __syncthreads();
    if (threadIdx.x < HD) {
        int c = threadIdx.x;
        float a1 = 0.f, a2 = 0.f;
#pragma unroll
        for (int i = 0; i < 8; ++i) { a1 += sh1[i][c]; a2 += sh2[i][c]; }
        atomicAdd(&colsum[c], a1);
        atomicAdd(&colsumsq[c], a2);
    }
}

__global__ void bn_finalize(const float* __restrict__ colsum, const float* __restrict__ colsumsq,
                            const float* __restrict__ gamma, const float* __restrict__ beta,
                            float* __restrict__ scale, float* __restrict__ shift) {
    int c = threadIdx.x;
    float invn = 1.0f / (float)NN;
    float m = colsum[c] * invn;
    float v = colsumsq[c] * invn - m * m;
    float sc = gamma[c] * rsqrtf(v + BN_EPS);
    scale[c] = sc;
    shift[c] = beta[c] - m * sc;
}

// h += relu(y*scale + shift);  y already includes dinv.
__global__ void bn_apply(const float* __restrict__ acc,
                         const float* __restrict__ scale, const float* __restrict__ shift,
                         float* __restrict__ h) {
    int idx = blockIdx.x * blockDim.x + threadIdx.x;
    int r = idx >> 5;
    int q = idx & 31;
    if (r >= NN) return;
    float4 a = *(const float4*)(acc + (size_t)r * HD + q * 4);
    float4 sc = *(const float4*)(scale + q * 4);
    float4 sf = *(const float4*)(shift + q * 4);
    float4* hp = (float4*)(h + (size_t)r * HD + q * 4);
    float4 hv = *hp;
    hv.x += fmaxf(fmaf(a.x, sc.x, sf.x), 0.f);
    hv.y += fmaxf(fmaf(a.y, sc.y, sf.y), 0.f);
    hv.z += fmaxf(fmaf(a.z, sc.z, sf.z), 0.f);
    hv.w += fmaxf(fmaf(a.w, sc.w, sf.w), 0.f);
    *hp = hv;
}

// gstart[g] = first node index with batch >= g (batch is sorted ascending).
__global__ void group_bounds(const int* __restrict__ batch, int* __restrict__ gstart) {
    int g = blockIdx.x * blockDim.x + threadIdx.x;
    if (g > NG) return;
    if (g == NG) { gstart[NG] = NN; return; }
    int lo = 0, hi = NN;
    while (lo < hi) {
        int mid = (lo + hi) >> 1;
        if (batch[mid] < g) lo = mid + 1; else hi = mid;
    }
    gstart[g] = lo;
}

// Fused last-layer bn_apply + mean-pool: pool[g][c] = mean(h + relu(y*scale+shift)).
// No write-back of h (h is dead after pooling).
__launch_bounds__(128)
__global__ void pool_bn_mean(const float* __restrict__ acc, const float* __restrict__ h,
                             const float* __restrict__ scale, const float* __restrict__ shift,
                             const int* __restrict__ gstart, float* __restrict__ pool) {
    int g = blockIdx.x;
    int c = threadIdx.x;
    float sc = scale[c], sf = shift[c];
    int s = gstart[g], e = gstart[g + 1];
    float a = 0.f;
    for (int r = s; r < e; ++r) {
        float y = fmaxf(fmaf(acc[(size_t)r * HD + c], sc, sf), 0.f);
        a += h[(size_t)r * HD + c] + y;
    }
    float ic = 1.0f / fmaxf((float)(e - s), 1.0f);
    pool[(size_t)g * HD + c] = a * ic;
}

__launch_bounds__(128)
__global__ void out_gemm(const float* __restrict__ pool,
                         const float* __restrict__ Wout, const float* __restrict__ bout,
                         float* __restrict__ out) {
    __shared__ float hb[HD];
    int g = blockIdx.x;
    int c = threadIdx.x;
    hb[c] = pool[(size_t)g * HD + c];
    __syncthreads();
    float o = bout[c];
#pragma unroll 8
    for (int k = 0; k < HD; ++k) o = fmaf(hb[k], Wout[k * HD + c], o);
    out[(size_t)g * HD + c] = o;
}

extern "C" void kernel_launch(void* const* d_in, const int* in_sizes, int n_in,
                              void* d_out, int out_size, void* d_ws, size_t ws_size,
                              hipStream_t stream) {
    const float* x      = (const float*)d_in[0];
    const float* W_in   = (const float*)d_in[1];
    const float* b_in   = (const float*)d_in[2];
    const float* W_conv = (const float*)d_in[3];
    // d_in[4] = b_conv — cancels exactly inside BatchNorm (mean shift only), unused.
    const float* gamma  = (const float*)d_in[5];
    const float* beta   = (const float*)d_in[6];
    const float* W_out  = (const float*)d_in[7];
    const float* b_out  = (const float*)d_in[8];
    const int*   edge   = (const int*)d_in[9];
    const int*   batch  = (const int*)d_in[10];
    float* out = (float*)d_out;

    char* ws = (char*)d_ws;
    float* dinv   = (float*)(ws + OFF_DINV);
    float* h      = (float*)(ws + OFF_H);
    float* u      = (float*)(ws + OFF_U);
    float* acc    = (float*)(ws + OFF_ACC);
    float* pool   = (float*)(ws + OFF_POOL);
    int*   gstart = (int*)(ws + OFF_GSTART);
    float* csum   = (float*)(ws + OFF_CSUM);
    float* csq    = (float*)(ws + OFF_CSQ);
    float* scale  = (float*)(ws + OFF_SCALE);
    float* shift  = (float*)(ws + OFF_SHIFT);
    int*   cnti   = (int*)(ws + OFF_CNTI);
    int*   offs   = (int*)(ws + OFF_OFFS);
    int*   cur    = (int*)(ws + OFF_CUR);
    int*   srcs   = (int*)(ws + OFF_SRCS);
    int*   bsum   = (int*)(ws + OFF_BSUM);

    const int* row = edge;        // sources
    const int* col = edge + NE;   // targets

    // zero: BN stats region, and cnti/cur region
    hipMemsetAsync(ws + OFF_CSUM, 0, OFF_SHIFT + 512 - OFF_CSUM, stream);
    hipMemsetAsync(ws + OFF_CNTI, 0, OFF_SRCS - OFF_CNTI, stream);

    // CSR build + dinv + group bounds
    count_deg_i<<<(NE + 255) / 256, 256, 0, stream>>>(col, cnti);
    finalize_dinv<<<(NN + 255) / 256, 256, 0, stream>>>(cnti, dinv);
    scan_phase1<<<SCAN_B, 256, 0, stream>>>(cnti, bsum);
    scan_phase2<<<1, 64, 0, stream>>>(bsum, offs);
    scan_phase3<<<SCAN_B, 256, 0, stream>>>(cnti, bsum, offs);
    fill_csr<<<(NE + 255) / 256, 256, 0, stream>>>(row, col, offs, cur, srcs);
    group_bounds<<<(NG + 256) / 256, 256, 0, stream>>>(batch, gstart);

    // h = x @ W_in + b_in
    gemm128<true, false><<<(NN + 255) / 256, 512, 0, stream>>>(
        x, W_in, b_in, nullptr, h, NN);

    for (int l = 0; l < NL; ++l) {
        // u = (h @ W_conv[l]) * dinv
        gemm128<false, true><<<(NN + 255) / 256, 512, 0, stream>>>(
            h, W_conv + (size_t)l * HD * HD, nullptr, dinv, u, NN);
        gather_bn<<<GATHER_BLOCKS, 256, 0, stream>>>(
            offs, srcs, u, dinv, acc, csum + l * HD, csq + l * HD);
        bn_finalize<<<1, HD, 0, stream>>>(
            csum + l * HD, csq + l * HD, gamma + l * HD, beta + l * HD, scale, shift);
        if (l < NL - 1) {
            bn_apply<<<((size_t)NN * 32 + 255) / 256, 256, 0, stream>>>(
                acc, scale, shift, h);
        }
    }

    // fused: pool[g] = mean(h + relu(acc*scale+shift)) over group rows
    pool_bn_mean<<<NG, 128, 0, stream>>>(acc, h, scale, shift, gstart, pool);
    out_gemm<<<NG, 128, 0, stream>>>(pool, W_out, b_out, out);
}

// Round 5
// 872.105 us; speedup vs baseline: 1.3401x; 1.3401x over previous
//
#include <hip/hip_runtime.h>

#define NN 200000
#define NE 400000
#define HD 128
#define NL 3
#define NG 4096
#define BN_EPS 1e-5f

// ---------------- workspace layout (bytes) ----------------
#define OFF_DINV  0UL                  // NN floats
#define OFF_H     800000UL             // NN*HD floats
#define OFF_U     103200000UL          // NN*HD floats
#define OFF_ACC   205600000UL          // NN*HD floats (holds y = dinv*agg)
#define OFF_POOL  308000000UL          // NG*HD floats (group means)
#define OFF_GSTART 310097152UL         // (NG+1) ints
#define OFF_CSUM  310113540UL          // NL*HD floats
#define OFF_CSQ   310115076UL          // NL*HD floats
#define OFF_SCALE 310116612UL          // HD floats
#define OFF_SHIFT 310117124UL          // HD floats
#define OFF_CNTI  310117636UL          // NN ints (in-degree, excl self)
#define OFF_OFFS  310917636UL          // (NN+1) ints + pad
#define OFF_CUR   311717652UL          // NN ints (fill cursors)
#define OFF_SRCS  312517652UL          // NE ints (CSR sources)
#define OFF_BSUM  314117652UL          // scan partials (256 ints)

#define SCAN_B 196                     // ceil(NN/1024)

typedef __attribute__((ext_vector_type(8))) short v8s;   // 8 bf16 (4 VGPRs)
typedef __attribute__((ext_vector_type(4))) float v4f;   // 4 fp32 acc

__global__ void count_deg_i(const int* __restrict__ col, int* __restrict__ cnt) {
    int e = blockIdx.x * blockDim.x + threadIdx.x;
    if (e < NE) atomicAdd(&cnt[col[e]], 1);
}

__global__ void finalize_dinv(const int* __restrict__ cnt, float* __restrict__ dinv) {
    int i = blockIdx.x * blockDim.x + threadIdx.x;
    if (i < NN) dinv[i] = rsqrtf((float)(cnt[i] + 1));   // +1 self-loop
}

// ---- exclusive scan of cnt[NN] -> offs[NN+1] (three phases) ----
__global__ void scan_phase1(const int* __restrict__ cnt, int* __restrict__ bsum) {
    __shared__ int sh[256];
    int b = blockIdx.x, t = threadIdx.x;
    int base = b * 1024 + t * 4;
    int s = 0;
#pragma unroll
    for (int j = 0; j < 4; ++j) if (base + j < NN) s += cnt[base + j];
    sh[t] = s;
    __syncthreads();
    for (int st = 128; st > 0; st >>= 1) {
        if (t < st) sh[t] += sh[t + st];
        __syncthreads();
    }
    if (t == 0) bsum[b] = sh[0];
}

__global__ void scan_phase2(int* __restrict__ bsum, int* __restrict__ offs) {
    if (threadIdx.x == 0) {
        int run = 0;
        for (int i = 0; i < SCAN_B; ++i) { int v = bsum[i]; bsum[i] = run; run += v; }
        offs[NN] = NE;
    }
}

__global__ void scan_phase3(const int* __restrict__ cnt, const int* __restrict__ bsum,
                            int* __restrict__ offs) {
    __shared__ int sh[256];
    int b = blockIdx.x, t = threadIdx.x;
    int base = b * 1024 + t * 4;
    int v[4];
    int s = 0;
#pragma unroll
    for (int j = 0; j < 4; ++j) { v[j] = (base + j < NN) ? cnt[base + j] : 0; s += v[j]; }
    sh[t] = s;
    __syncthreads();
    for (int st = 1; st < 256; st <<= 1) {
        int x = (t >= st) ? sh[t - st] : 0;
        __syncthreads();
        sh[t] += x;
        __syncthreads();
    }
    int run = sh[t] - s + bsum[b];   // exclusive prefix for this thread's range
#pragma unroll
    for (int j = 0; j < 4; ++j) {
        if (base + j < NN) { offs[base + j] = run; run += v[j]; }
    }
}

__global__ void fill_csr(const int* __restrict__ row, const int* __restrict__ col,
                         const int* __restrict__ offs, int* __restrict__ cur,
                         int* __restrict__ srcs) {
    int e = blockIdx.x * blockDim.x + threadIdx.x;
    if (e >= NE) return;
    int c = col[e];
    int p = offs[c] + atomicAdd(&cur[c], 1);
    srcs[p] = row[e];
}

// float -> (bf16 hi RNE, bf16 lo RNE of exact residual)
__device__ inline void cvt_split(float f, short& hi, short& lo) {
    unsigned u = __float_as_uint(f);
    unsigned rh = (u + 0x7fffu + ((u >> 16) & 1u)) >> 16;
    hi = (short)rh;
    float fh = __uint_as_float(rh << 16);
    float d = f - fh;                      // exact in fp32
    unsigned u2 = __float_as_uint(d);
    unsigned rl = (u2 + 0x7fffu + ((u2 >> 16) & 1u)) >> 16;
    lo = (short)rl;
}

// O = A @ W (+bias) (*dinv), via MFMA 16x16x32 bf16 with bf16x3 split.
// Block: 256 thr = 4 waves; W (128x128 fp32) converted once per block into LDS
// as transposed hi/lo bf16, XOR-swizzled granules (bank-uniform b128 reads).
// Each wave: 32 rows per task (2 strips of 16). Grid-stride over 128-row tasks.
#define GEMM_BLOCKS 512
template <bool ADD_BIAS, bool SCALE_DINV>
__launch_bounds__(256, 2)
__global__ void gemm_mfma(const float* __restrict__ A, const float* __restrict__ W,
                          const float* __restrict__ bias, const float* __restrict__ dinv,
                          float* __restrict__ O, int M) {
    __shared__ short Wh[HD * HD];   // Wt[c][k] hi, granule G stored at G^(c&7)
    __shared__ short Wlo[HD * HD];  // Wt[c][k] lo

    {   // stage + convert + transpose + swizzle W
        int c = threadIdx.x >> 1;
        int half = threadIdx.x & 1;
        for (int g8 = 0; g8 < 8; ++g8) {
            int G = half * 8 + g8;
            v8s h8, l8;
#pragma unroll
            for (int j = 0; j < 8; ++j) {
                float f = W[(G * 8 + j) * HD + c];
                short hi, lo;
                cvt_split(f, hi, lo);
                h8[j] = hi; l8[j] = lo;
            }
            int off = c * HD + (G ^ (c & 7)) * 8;
            *(v8s*)&Wh[off] = h8;
            *(v8s*)&Wlo[off] = l8;
        }
    }
    __syncthreads();

    int wave = threadIdx.x >> 6;
    int lane = threadIdx.x & 63;
    int m = lane & 15;        // A-row / B-col lane index
    int q = lane >> 4;        // quad

    for (int task = blockIdx.x; task * 128 < M; task += GEMM_BLOCKS) {
        int rbase = task * 128 + wave * 32;
        if (rbase >= M) continue;

        // load + split A fragments: 2 strips x 4 k-chunks
        v8s ah[2][4], al[2][4];
        int nstrip = (rbase + 16 < M) ? 2 : 1;   // strips are 16-aligned; M%16==0
#pragma unroll
        for (int s = 0; s < 2; ++s) {
            if (s >= nstrip) break;
            const float* Ar = A + (size_t)(rbase + s * 16 + m) * HD;
#pragma unroll
            for (int kc = 0; kc < 4; ++kc) {
                float4 x0 = *(const float4*)(Ar + kc * 32 + q * 8);
                float4 x1 = *(const float4*)(Ar + kc * 32 + q * 8 + 4);
                float xs[8] = {x0.x, x0.y, x0.z, x0.w, x1.x, x1.y, x1.z, x1.w};
                v8s h8, l8;
#pragma unroll
                for (int j = 0; j < 8; ++j) {
                    short hi, lo;
                    cvt_split(xs[j], hi, lo);
                    h8[j] = hi; l8[j] = lo;
                }
                ah[s][kc] = h8; al[s][kc] = l8;
            }
        }

        v4f acc[2][8];
#pragma unroll
        for (int s = 0; s < 2; ++s)
#pragma unroll
            for (int ct = 0; ct < 8; ++ct)
                acc[s][ct] = (v4f){0.f, 0.f, 0.f, 0.f};

        for (int kc = 0; kc < 4; ++kc) {
#pragma unroll
            for (int ct = 0; ct < 8; ++ct) {
                int c = ct * 16 + m;
                int off = c * HD + (((kc * 4 + q) ^ (c & 7)) * 8);
                v8s bh = *(const v8s*)&Wh[off];
                v8s bl = *(const v8s*)&Wlo[off];
                acc[0][ct] = __builtin_amdgcn_mfma_f32_16x16x32_bf16(ah[0][kc], bh, acc[0][ct], 0, 0, 0);
                acc[1][ct] = __builtin_amdgcn_mfma_f32_16x16x32_bf16(ah[1][kc], bh, acc[1][ct], 0, 0, 0);
                acc[0][ct] = __builtin_amdgcn_mfma_f32_16x16x32_bf16(al[0][kc], bh, acc[0][ct], 0, 0, 0);
                acc[1][ct] = __builtin_amdgcn_mfma_f32_16x16x32_bf16(al[1][kc], bh, acc[1][ct], 0, 0, 0);
                acc[0][ct] = __builtin_amdgcn_mfma_f32_16x16x32_bf16(ah[0][kc], bl, acc[0][ct], 0, 0, 0);
                acc[1][ct] = __builtin_amdgcn_mfma_f32_16x16x32_bf16(ah[1][kc], bl, acc[1][ct], 0, 0, 0);
            }
        }

        // epilogue: D lane mapping col=lane&15, row=(lane>>4)*4+reg
#pragma unroll
        for (int s = 0; s < 2; ++s) {
            if (s >= nstrip) break;
            int rs = rbase + s * 16;
            float dv[4];
#pragma unroll
            for (int reg = 0; reg < 4; ++reg)
                dv[reg] = SCALE_DINV ? dinv[rs + q * 4 + reg] : 1.0f;
#pragma unroll
            for (int ct = 0; ct < 8; ++ct) {
                int colb = ct * 16 + m;
                float bb = ADD_BIAS ? bias[colb] : 0.0f;
#pragma unroll
                for (int reg = 0; reg < 4; ++reg) {
                    int r = rs + q * 4 + reg;
                    float v = acc[s][ct][reg] + bb;
                    if (SCALE_DINV) v *= dv[reg];
                    O[(size_t)r * HD + colb] = v;
                }
            }
        }
    }
}

// acc[i] = y_i = dinv[i]*(u[i] + sum_{e: col=i} u[src[e]]); fused BN col stats.
#define GATHER_BLOCKS 1024
__global__ void gather_bn(const int* __restrict__ offs, const int* __restrict__ srcs,
                          const float* __restrict__ u, const float* __restrict__ dinv,
                          float* __restrict__ acc,
                          float* __restrict__ colsum, float* __restrict__ colsumsq) {
    const float4* u4 = (const float4*)u;
    float4* acc4 = (float4*)acc;
    int n = threadIdx.x >> 5;     // node slot 0..7
    int q = threadIdx.x & 31;     // float4 lane within row
    float4 t1 = make_float4(0.f, 0.f, 0.f, 0.f);
    float4 t2 = make_float4(0.f, 0.f, 0.f, 0.f);

    for (int node = blockIdx.x * 8 + n; node < NN; node += GATHER_BLOCKS * 8) {
        float4 s = u4[(size_t)node * 32 + q];     // self-loop seed
        int k1 = offs[node + 1];
        for (int k = offs[node]; k < k1; ++k) {
            int src = srcs[k];
            float4 v = u4[(size_t)src * 32 + q];
            s.x += v.x; s.y += v.y; s.z += v.z; s.w += v.w;
        }
        float d = dinv[node];
        s.x *= d; s.y *= d; s.z *= d; s.w *= d;
        acc4[(size_t)node * 32 + q] = s;
        t1.x += s.x; t1.y += s.y; t1.z += s.z; t1.w += s.w;
        t2.x += s.x * s.x; t2.y += s.y * s.y; t2.z += s.z * s.z; t2.w += s.w * s.w;
    }

    __shared__ float sh1[8][HD];
    __shared__ float sh2[8][HD];
    *(float4*)&sh1[n][q * 4] = t1;
    *(float4*)&sh2[n][q * 4] = t2;
    __syncthreads();
    if (threadIdx.x < HD) {
        int c = threadIdx.x;
        float a1 = 0.f, a2 = 0.f;
#pragma unroll
        for (int i = 0; i < 8; ++i) { a1 += sh1[i][c]; a2 += sh2[i][c]; }
        atomicAdd(&colsum[c], a1);
        atomicAdd(&colsumsq[c], a2);
    }
}

__global__ void bn_finalize(const float* __restrict__ colsum, const float* __restrict__ colsumsq,
                            const float* __restrict__ gamma, const float* __restrict__ beta,
                            float* __restrict__ scale, float* __restrict__ shift) {
    int c = threadIdx.x;
    float invn = 1.0f / (float)NN;
    float m = colsum[c] * invn;
    float v = colsumsq[c] * invn - m * m;
    float sc = gamma[c] * rsqrtf(v + BN_EPS);
    scale[c] = sc;
    shift[c] = beta[c] - m * sc;
}

// h += relu(y*scale + shift);  y already includes dinv.
__global__ void bn_apply(const float* __restrict__ acc,
                         const float* __restrict__ scale, const float* __restrict__ shift,
                         float* __restrict__ h) {
    int idx = blockIdx.x * blockDim.x + threadIdx.x;
    int r = idx >> 5;
    int q = idx & 31;
    if (r >= NN) return;
    float4 a = *(const float4*)(acc + (size_t)r * HD + q * 4);
    float4 sc = *(const float4*)(scale + q * 4);
    float4 sf = *(const float4*)(shift + q * 4);
    float4* hp = (float4*)(h + (size_t)r * HD + q * 4);
    float4 hv = *hp;
    hv.x += fmaxf(fmaf(a.x, sc.x, sf.x), 0.f);
    hv.y += fmaxf(fmaf(a.y, sc.y, sf.y), 0.f);
    hv.z += fmaxf(fmaf(a.z, sc.z, sf.z), 0.f);
    hv.w += fmaxf(fmaf(a.w, sc.w, sf.w), 0.f);
    *hp = hv;
}

// gstart[g] = first node index with batch >= g (batch is sorted ascending).
__global__ void group_bounds(const int* __restrict__ batch, int* __restrict__ gstart) {
    int g = blockIdx.x * blockDim.x + threadIdx.x;
    if (g > NG) return;
    if (g == NG) { gstart[NG] = NN; return; }
    int lo = 0, hi = NN;
    while (lo < hi) {
        int mid = (lo + hi) >> 1;
        if (batch[mid] < g) lo = mid + 1; else hi = mid;
    }
    gstart[g] = lo;
}

// Fused last-layer bn_apply + mean-pool: pool[g][c] = mean(h + relu(y*scale+shift)).
__launch_bounds__(128)
__global__ void pool_bn_mean(const float* __restrict__ acc, const float* __restrict__ h,
                             const float* __restrict__ scale, const float* __restrict__ shift,
                             const int* __restrict__ gstart, float* __restrict__ pool) {
    int g = blockIdx.x;
    int c = threadIdx.x;
    float sc = scale[c], sf = shift[c];
    int s = gstart[g], e = gstart[g + 1];
    float a = 0.f;
    for (int r = s; r < e; ++r) {
        float y = fmaxf(fmaf(acc[(size_t)r * HD + c], sc, sf), 0.f);
        a += h[(size_t)r * HD + c] + y;
    }
    float ic = 1.0f / fmaxf((float)(e - s), 1.0f);
    pool[(size_t)g * HD + c] = a * ic;
}

__launch_bounds__(128)
__global__ void out_gemm(const float* __restrict__ pool,
                         const float* __restrict__ Wout, const float* __restrict__ bout,
                         float* __restrict__ out) {
    __shared__ float hb[HD];
    int g = blockIdx.x;
    int c = threadIdx.x;
    hb[c] = pool[(size_t)g * HD + c];
    __syncthreads();
    float o = bout[c];
#pragma unroll 8
    for (int k = 0; k < HD; ++k) o = fmaf(hb[k], Wout[k * HD + c], o);
    out[(size_t)g * HD + c] = o;
}

extern "C" void kernel_launch(void* const* d_in, const int* in_sizes, int n_in,
                              void* d_out, int out_size, void* d_ws, size_t ws_size,
                              hipStream_t stream) {
    const float* x      = (const float*)d_in[0];
    const float* W_in   = (const float*)d_in[1];
    const float* b_in   = (const float*)d_in[2];
    const float* W_conv = (const float*)d_in[3];
    // d_in[4] = b_conv — cancels exactly inside BatchNorm (mean shift only), unused.
    const float* gamma  = (const float*)d_in[5];
    const float* beta   = (const float*)d_in[6];
    const float* W_out  = (const float*)d_in[7];
    const float* b_out  = (const float*)d_in[8];
    const int*   edge   = (const int*)d_in[9];
    const int*   batch  = (const int*)d_in[10];
    float* out = (float*)d_out;

    char* ws = (char*)d_ws;
    float* dinv   = (float*)(ws + OFF_DINV);
    float* h      = (float*)(ws + OFF_H);
    float* u      = (float*)(ws + OFF_U);
    float* acc    = (float*)(ws + OFF_ACC);
    float* pool   = (float*)(ws + OFF_POOL);
    int*   gstart = (int*)(ws + OFF_GSTART);
    float* csum   = (float*)(ws + OFF_CSUM);
    float* csq    = (float*)(ws + OFF_CSQ);
    float* scale  = (float*)(ws + OFF_SCALE);
    float* shift  = (float*)(ws + OFF_SHIFT);
    int*   cnti   = (int*)(ws + OFF_CNTI);
    int*   offs   = (int*)(ws + OFF_OFFS);
    int*   cur    = (int*)(ws + OFF_CUR);
    int*   srcs   = (int*)(ws + OFF_SRCS);
    int*   bsum   = (int*)(ws + OFF_BSUM);

    const int* row = edge;        // sources
    const int* col = edge + NE;   // targets

    // zero: BN stats region, and cnti/cur region
    hipMemsetAsync(ws + OFF_CSUM, 0, OFF_SHIFT + 512 - OFF_CSUM, stream);
    hipMemsetAsync(ws + OFF_CNTI, 0, OFF_SRCS - OFF_CNTI, stream);

    // CSR build + dinv + group bounds
    count_deg_i<<<(NE + 255) / 256, 256, 0, stream>>>(col, cnti);
    finalize_dinv<<<(NN + 255) / 256, 256, 0, stream>>>(cnti, dinv);
    scan_phase1<<<SCAN_B, 256, 0, stream>>>(cnti, bsum);
    scan_phase2<<<1, 64, 0, stream>>>(bsum, offs);
    scan_phase3<<<SCAN_B, 256, 0, stream>>>(cnti, bsum, offs);
    fill_csr<<<(NE + 255) / 256, 256, 0, stream>>>(row, col, offs, cur, srcs);
    group_bounds<<<(NG + 256) / 256, 256, 0, stream>>>(batch, gstart);

    // h = x @ W_in + b_in
    gemm_mfma<true, false><<<GEMM_BLOCKS, 256, 0, stream>>>(
        x, W_in, b_in, nullptr, h, NN);

    for (int l = 0; l < NL; ++l) {
        // u = (h @ W_conv[l]) * dinv
        gemm_mfma<false, true><<<GEMM_BLOCKS, 256, 0, stream>>>(
            h, W_conv + (size_t)l * HD * HD, nullptr, dinv, u, NN);
        gather_bn<<<GATHER_BLOCKS, 256, 0, stream>>>(
            offs, srcs, u, dinv, acc, csum + l * HD, csq + l * HD);
        bn_finalize<<<1, HD, 0, stream>>>(
            csum + l * HD, csq + l * HD, gamma + l * HD, beta + l * HD, scale, shift);
        if (l < NL - 1) {
            bn_apply<<<((size_t)NN * 32 + 255) / 256, 256, 0, stream>>>(
                acc, scale, shift, h);
        }
    }

    // fused: pool[g] = mean(h + relu(acc*scale+shift)) over group rows
    pool_bn_mean<<<NG, 128, 0, stream>>>(acc, h, scale, shift, gstart, pool);
    out_gemm<<<NG, 128, 0, stream>>>(pool, W_out, b_out, out);
}